// Round 7
// baseline (2237.087 us; speedup 1.0000x reference)
//
#include <hip/hip_runtime.h>
#include <cstddef>

#define Bn 32
#define Sn 2048
#define Hn 256
#define Ln 2
#define CHUNK 64
#define NCHUNK (Sn / CHUNK)   // 32

#define PSTRIDE 9
#define PBUF (Hn * PSTRIDE)   // 2304 words per partial buffer

#define FPAD 32               // one flag per 128B: no L3 line contention

// ---------------------------------------------------------------------------
// Pipeline flags (chunk-granular monotone counters), zeroed each launch.
//   slot (0,b): xp1[b] chunks ready   (proj1 publishes)
//   slot (1,b): y1[b] chunks done     (rec1 publishes)
//   slot (2,b): xp2[b] chunks ready   (proj2 publishes)
// All data that crosses blocks goes through sc1 (device-scope) accesses, so
// no threadfence / bulk L2 maintenance is needed anywhere.
// ---------------------------------------------------------------------------
__device__ unsigned g_flags[3 * Bn * FPAD];

__global__ void zero_flags_k() {
  int i = threadIdx.x;
  if (i < 3 * Bn)
    __hip_atomic_store(&g_flags[i * FPAD], 0u, __ATOMIC_RELAXED,
                       __HIP_MEMORY_SCOPE_AGENT);
}

__device__ __forceinline__ float tanh_fast(float x) {
  // tanh(x) = 1 - 2/(exp(2x)+1); saturates correctly at +/-inf
  float e = __expf(2.0f * x);
  return 1.0f - 2.0f / (e + 1.0f);
}

// device-scope (sc1) scalar data ops: read/write the L3 coherence point,
// bypassing the (non-XCD-coherent) L2. Relaxed: no cache maintenance.
__device__ __forceinline__ float ldg_dev(const float* p) {
  return __hip_atomic_load(p, __ATOMIC_RELAXED, __HIP_MEMORY_SCOPE_AGENT);
}
__device__ __forceinline__ void stg_dev(float* p, float v) {
  __hip_atomic_store(p, v, __ATOMIC_RELAXED, __HIP_MEMORY_SCOPE_AGENT);
}

// relaxed poll; NO fence (data is read via ldg_dev by the consumer)
__device__ __forceinline__ void wait_ge(unsigned* f, unsigned tgt) {
  while (__hip_atomic_load(f, __ATOMIC_RELAXED, __HIP_MEMORY_SCOPE_AGENT) < tgt)
    __builtin_amdgcn_s_sleep(8);
}

// publisher: all threads drain stores (sc1 stores retire at the coherence
// point), barrier, then t0 stores the flag. NO fence.
__device__ __forceinline__ void publish(unsigned* f, unsigned val, int t) {
  asm volatile("s_waitcnt vmcnt(0)" ::: "memory");
  __syncthreads();
  if (t == 0)
    __hip_atomic_store(f, val, __ATOMIC_RELAXED, __HIP_MEMORY_SCOPE_AGENT);
}

// ---------------------------------------------------------------------------
// Recurrence body — EXACT round-2 step structure (603 ns/step standalone, 0
// LDS conflicts), chunked with flag wait/publish and DEPTH-2 xp prefetch.
//   wave w owns k-chunk [32w,32w+32) and outputs [32w,32w+32)
//   partials at part[9*o + w]: write bank (9l+w)%32 -> 2-way only (free)
//   single raw s_barrier per step, partials double-buffered on (s&1)
//   reduce: lane sums 4 of 8 slots + one shfl_xor(32)
//   h exchange via hbuf LDS (wave-local readback, wave_barrier only)
// xp is consumed via ldg_dev (proj may have written it from another XCD);
// y is produced via stg_dev (proj2 on another XCD reads it).
// ---------------------------------------------------------------------------
__device__ void rec_body(const float* __restrict__ xp_b,
                         const float* __restrict__ Whh,
                         const float* __restrict__ bhh,
                         const float* __restrict__ h0_b,
                         float* __restrict__ y_b,
                         float* __restrict__ hfin_b,
                         unsigned* waitf, unsigned* pub,
                         float* part, float* hbuf) {
  const int t = threadIdx.x;
  const int lane = t & 63;
  const int w = t >> 6;                   // 0..7
  const int ocol = 32 * w + (lane & 31);  // output this lane reduces
  const int hh = lane >> 5;               // which half of the 8 slots

  // Wreg[r][c] = Whh[lane + 64r][32w + c]
  float Wreg[4][32];
#pragma unroll
  for (int r = 0; r < 4; ++r)
#pragma unroll
    for (int q = 0; q < 8; ++q) {
      float4 v = *(const float4*)&Whh[(size_t)(lane + 64 * r) * Hn + 32 * w + 4 * q];
      Wreg[r][4 * q + 0] = v.x; Wreg[r][4 * q + 1] = v.y;
      Wreg[r][4 * q + 2] = v.z; Wreg[r][4 * q + 3] = v.w;
    }

  const int pw0 = PSTRIDE * lane + w;
  const float bias = bhh[ocol];

  float hv[32];
#pragma unroll
  for (int j = 0; j < 8; ++j)
    *(float4*)&hv[4 * j] = *(const float4*)&h0_b[32 * w + 4 * j];

  for (int c = 0; c < NCHUNK; ++c) {
    // acquire this chunk's xp
    if (t == 0) wait_ge(waitf, c + 1);
    __syncthreads();

    const int s0 = c * CHUNK;
    // fresh loads of the two slots the cross-chunk prefetch may have staled
    float xp_cur = ldg_dev(&xp_b[(size_t)s0 * Hn + ocol]);
    float xp_n1  = ldg_dev(&xp_b[(size_t)(s0 + 1) * Hn + ocol]);

    for (int ss = 0; ss < CHUNK; ++ss) {
      const int s = s0 + ss;
      // depth-2 prefetch: consumed two steps later (~1.2us of cover)
      float xp_n2 = (s + 2 < Sn) ? ldg_dev(&xp_b[(size_t)(s + 2) * Hn + ocol])
                                 : 0.0f;

      float a0 = 0.f, a1 = 0.f, a2 = 0.f, a3 = 0.f;
#pragma unroll
      for (int cc = 0; cc < 32; ++cc) {
        a0 += Wreg[0][cc] * hv[cc];
        a1 += Wreg[1][cc] * hv[cc];
        a2 += Wreg[2][cc] * hv[cc];
        a3 += Wreg[3][cc] * hv[cc];
      }
      float* pbuf = &part[(s & 1) * PBUF];
      pbuf[pw0       ] = a0;
      pbuf[pw0 +  576] = a1;
      pbuf[pw0 + 1152] = a2;
      pbuf[pw0 + 1728] = a3;

      asm volatile("s_waitcnt lgkmcnt(0)" ::: "memory");
      __builtin_amdgcn_s_barrier();
      __builtin_amdgcn_sched_barrier(0);

      const float* prow = &pbuf[PSTRIDE * ocol + 4 * hh];
      float r0 = prow[0], r1 = prow[1], r2 = prow[2], r3 = prow[3];
      float s4 = (r0 + r1) + (r2 + r3);
      float tot = s4 + __shfl_xor(s4, 32, 64);
      float hn = tanh_fast(tot + xp_cur + bias);
      if (lane < 32) {
        hbuf[ocol] = hn;
        stg_dev(&y_b[(size_t)s * Hn + ocol], hn);   // fire-and-forget, sc1
      }
      xp_cur = xp_n1;
      xp_n1 = xp_n2;

      __builtin_amdgcn_wave_barrier();     // keep reads after the write
#pragma unroll
      for (int j = 0; j < 8; ++j)
        *(float4*)&hv[4 * j] = *(const float4*)&hbuf[32 * w + 4 * j];
    }

    if (pub) publish(pub, (unsigned)(c + 1), t);
  }

  if (lane < 32) hfin_b[ocol] = hbuf[ocol];
}

// ---------------------------------------------------------------------------
// Projection worker: one block per (layer, batch). Per chunk c: full-width
//   C[64,256] = A[64,256] * W[256,256]^T + bias   as 4 64x64 N-tiles.
// 512 threads; K staged in 64-chunks, k ascending -> summation order
// identical to all prior rounds (absmax-stable). ~14us/chunk << 38.6us
// rec cadence, so proj never gates steady state.
// a_sc: proj2 reads y1 (produced by rec1 on another XCD) -> sc1 scalar
// loads; proj1 reads the kernel input x -> normal cached float4 loads.
// C (xp) is always written via stg_dev (consumed cross-XCD by rec).
// ---------------------------------------------------------------------------
__device__ void proj_body(const float* __restrict__ Ab,
                          const float* __restrict__ W,
                          const float* __restrict__ bias,
                          float* __restrict__ Cb,
                          unsigned* waitf, unsigned* pub, bool a_sc,
                          float* smem) {
  const int t = threadIdx.x;
  const int tx = t & 15;    // 4 cols each
  const int ty = t >> 4;    // 0..31, 2 rows each
  float (*As)[68] = (float(*)[68])smem;
  float (*Bs)[68] = (float(*)[68])(smem + 64 * 68);

  for (int c = 0; c < NCHUNK; ++c) {
    if (waitf) {
      if (t == 0) wait_ge(waitf, c + 1);
      __syncthreads();
    }
    const float* A = Ab + (size_t)(c * CHUNK) * Hn;
    float* C = Cb + (size_t)(c * CHUNK) * Hn;

    for (int nt = 0; nt < 4; ++nt) {
      const int n0 = nt * 64;
      float acc[2][4] = {{0.f, 0.f, 0.f, 0.f}, {0.f, 0.f, 0.f, 0.f}};
      for (int kc = 0; kc < Hn; kc += 64) {
#pragma unroll
        for (int r = 0; r < 2; ++r) {
          int idx = t + 512 * r;           // 0..1023 -> 64 rows x 16 float4
          int mm = idx >> 4;
          int kk = (idx & 15) << 2;
          if (a_sc) {
            const float* ap = &A[(size_t)mm * Hn + kc + kk];
            As[kk + 0][mm] = ldg_dev(ap + 0);
            As[kk + 1][mm] = ldg_dev(ap + 1);
            As[kk + 2][mm] = ldg_dev(ap + 2);
            As[kk + 3][mm] = ldg_dev(ap + 3);
          } else {
            float4 av = *(const float4*)&A[(size_t)mm * Hn + kc + kk];
            As[kk + 0][mm] = av.x; As[kk + 1][mm] = av.y;
            As[kk + 2][mm] = av.z; As[kk + 3][mm] = av.w;
          }
          float4 wv = *(const float4*)&W[(size_t)(n0 + mm) * Hn + kc + kk];
          Bs[kk + 0][mm] = wv.x; Bs[kk + 1][mm] = wv.y;
          Bs[kk + 2][mm] = wv.z; Bs[kk + 3][mm] = wv.w;
        }
        __syncthreads();
#pragma unroll
        for (int k = 0; k < 64; ++k) {
          float a0 = As[k][2 * ty], a1 = As[k][2 * ty + 1];
          float4 bv = *(const float4*)&Bs[k][tx << 2];
          acc[0][0] += a0 * bv.x; acc[0][1] += a0 * bv.y;
          acc[0][2] += a0 * bv.z; acc[0][3] += a0 * bv.w;
          acc[1][0] += a1 * bv.x; acc[1][1] += a1 * bv.y;
          acc[1][2] += a1 * bv.z; acc[1][3] += a1 * bv.w;
        }
        __syncthreads();
      }
      float4 bb = *(const float4*)&bias[n0 + (tx << 2)];
#pragma unroll
      for (int i = 0; i < 2; ++i) {
        float* cp = &C[(size_t)(2 * ty + i) * Hn + n0 + (tx << 2)];
        stg_dev(cp + 0, acc[i][0] + bb.x);
        stg_dev(cp + 1, acc[i][1] + bb.y);
        stg_dev(cp + 2, acc[i][2] + bb.z);
        stg_dev(cp + 3, acc[i][3] + bb.w);
      }
    }

    if (pub) publish(pub, (unsigned)(c + 1), t);
  }
}

// ---------------------------------------------------------------------------
// Fused pipeline kernel. 128 blocks x 512 threads:
//   [  0, 32): rec1, batch b    waits xp1[b], publishes y1[b]
//   [ 32, 64): rec2, batch b    waits xp2[b]
//   [ 64, 96): proj1, batch b   publishes xp1[b]
//   [ 96,128): proj2, batch b   waits y1[b], publishes xp2[b]
// xp2 overwrites xp1 in place in ws (proj2 writes chunk c only after rec1
// published chunk c; rec1's prefetches into c+1 drained at that publish's
// vmcnt(0)), so ws stays 64 MiB.
// ---------------------------------------------------------------------------
__global__ __launch_bounds__(512) void fused(
    const float* __restrict__ x, const float* __restrict__ h0,
    const float* __restrict__ Wih, const float* __restrict__ Whh,
    const float* __restrict__ bih, const float* __restrict__ bhh,
    float* __restrict__ yout, float* __restrict__ fin,
    float* __restrict__ xpws) {
  __shared__ float smem[2 * 64 * 68];   // 34.8 KB; rec carves part+hbuf
  const int bid = blockIdx.x;

  if (bid < 32) {
    const int b = bid;
    rec_body(xpws + (size_t)b * Sn * Hn, Whh, bhh, h0 + (size_t)b * Hn,
             yout + (size_t)b * Sn * Hn, fin + (size_t)b * Hn,
             &g_flags[(0 * Bn + b) * FPAD], &g_flags[(1 * Bn + b) * FPAD],
             smem, smem + 2 * PBUF);
  } else if (bid < 64) {
    const int b = bid - 32;
    rec_body(xpws + (size_t)b * Sn * Hn, Whh + Hn * Hn, bhh + Hn,
             h0 + (size_t)Bn * Hn + (size_t)b * Hn,
             yout + (size_t)b * Sn * Hn, fin + (size_t)Bn * Hn + (size_t)b * Hn,
             &g_flags[(2 * Bn + b) * FPAD], nullptr,
             smem, smem + 2 * PBUF);
  } else if (bid < 96) {
    const int b = bid - 64;
    proj_body(x + (size_t)b * Sn * Hn, Wih, bih, xpws + (size_t)b * Sn * Hn,
              nullptr, &g_flags[(0 * Bn + b) * FPAD], false, smem);
  } else {
    const int b = bid - 96;
    proj_body(yout + (size_t)b * Sn * Hn, Wih + Hn * Hn, bih + Hn,
              xpws + (size_t)b * Sn * Hn,
              &g_flags[(1 * Bn + b) * FPAD], &g_flags[(2 * Bn + b) * FPAD],
              true, smem);
  }
}

// ---------------------------------------------------------------------------
// Launch: zero flags, then the single fused pipeline kernel.
// ws needs Bn*Sn*Hn*4 = 64 MiB (xp buffer, shared by both layers in-place).
// ---------------------------------------------------------------------------
extern "C" void kernel_launch(void* const* d_in, const int* in_sizes, int n_in,
                              void* d_out, int out_size, void* d_ws, size_t ws_size,
                              hipStream_t stream) {
  const float* x   = (const float*)d_in[0];
  const float* h0  = (const float*)d_in[1];
  const float* Wih = (const float*)d_in[2];
  const float* Whh = (const float*)d_in[3];
  const float* bih = (const float*)d_in[4];
  const float* bhh = (const float*)d_in[5];

  float* out = (float*)d_out;
  float* yout = out;                              // [Bn,Sn,Hn]
  float* fin  = out + (size_t)Bn * Sn * Hn;       // [Ln,Bn,Hn]
  float* xpws = (float*)d_ws;                     // [Bn,Sn,Hn] scratch

  zero_flags_k<<<1, 128, 0, stream>>>();
  fused<<<128, 512, 0, stream>>>(x, h0, Wih, Whh, bih, bhh, yout, fin, xpws);
}

// Round 8
// 2056.466 us; speedup vs baseline: 1.0878x; 1.0878x over previous
//
#include <hip/hip_runtime.h>
#include <cstddef>

#define Bn 32
#define Sn 2048
#define Hn 256
#define Ln 2
#define CHUNK 64
#define NCHUNK (Sn / CHUNK)   // 32

#define PSTRIDE 9
#define PBUF (Hn * PSTRIDE)   // 2304 words per partial buffer

#define FPAD 32               // one flag per 128B line
#define NFL (7 * Bn)          // 2 xp1-half + 1 y1 + 4 xp2-quarter, per batch

// ---------------------------------------------------------------------------
// Pipeline flags (chunk-granular monotone counters), zeroed each launch.
//   slot (0..1, b): xp1[b] ready, N-half j      (proj1 half-blocks publish)
//   slot (2,    b): y1[b] chunks done           (rec1 publishes)
//   slot (3..6, b): xp2[b] ready, N-quarter q   (proj2 tile-blocks publish)
// Multi-producer handoffs use SEPARATE flags (a summed counter is unsafe
// under producer skew); consumers poll each, then fence ONCE.
// ---------------------------------------------------------------------------
__device__ unsigned g_flags[NFL * FPAD];

__global__ void zero_flags_k() {
  int i = threadIdx.x;
  if (i < NFL)
    __hip_atomic_store(&g_flags[i * FPAD], 0u, __ATOMIC_RELAXED,
                       __HIP_MEMORY_SCOPE_AGENT);
}

__device__ __forceinline__ float tanh_fast(float x) {
  // tanh(x) = 1 - 2/(exp(2x)+1); saturates correctly at +/-inf
  float e = __expf(2.0f * x);
  return 1.0f - 2.0f / (e + 1.0f);
}

// RELAXED poll over n flags (stride Bn*FPAD apart), then ONE fence.
// (r6-proven protocol: no per-poll invalidate storm, one inv/wb per handoff)
__device__ __forceinline__ void wait_ge_n(unsigned* base, int n, unsigned tgt) {
  for (int q = 0; q < n; ++q) {
    unsigned* f = base + (size_t)q * Bn * FPAD;
    while (__hip_atomic_load(f, __ATOMIC_RELAXED, __HIP_MEMORY_SCOPE_AGENT) < tgt)
      __builtin_amdgcn_s_sleep(2);
  }
  __threadfence();   // one inv/wb per handoff, not per poll
}

// publisher: all threads drain stores, barrier, t0 fences (wb) + stores flag
__device__ __forceinline__ void publish(unsigned* f, unsigned val, int t) {
  asm volatile("s_waitcnt vmcnt(0)" ::: "memory");
  __syncthreads();
  if (t == 0) {
    __threadfence();
    __hip_atomic_store(f, val, __ATOMIC_RELAXED, __HIP_MEMORY_SCOPE_AGENT);
  }
}

// ---------------------------------------------------------------------------
// Recurrence body — EXACT round-2 step structure (603 ns/step standalone, 0
// LDS conflicts), chunked with flag wait/publish and depth-2 xp prefetch.
//   wave w owns k-chunk [32w,32w+32) and outputs [32w,32w+32)
//   partials at part[9*o + w]: write bank (9l+w)%32 -> 2-way only (free)
//   single raw s_barrier per step, partials double-buffered on (s&1)
//   reduce: lane sums 4 of 8 slots + one shfl_xor(32)
//   h exchange via hbuf LDS (wave-local readback, wave_barrier only)
// Chunk boundary: t0 polls its wait-flags + one fence, syncthreads, first
// TWO xp slots reloaded fresh (exactly the cross-chunk prefetch targets).
// ---------------------------------------------------------------------------
__device__ void rec_body(const float* __restrict__ xp_b,
                         const float* __restrict__ Whh,
                         const float* __restrict__ bhh,
                         const float* __restrict__ h0_b,
                         float* __restrict__ y_b,
                         float* __restrict__ hfin_b,
                         unsigned* wbase, int nw, unsigned* pub,
                         float* part, float* hbuf) {
  const int t = threadIdx.x;
  const int lane = t & 63;
  const int w = t >> 6;                   // 0..7
  const int ocol = 32 * w + (lane & 31);  // output this lane reduces
  const int hh = lane >> 5;               // which half of the 8 slots

  // Wreg[r][c] = Whh[lane + 64r][32w + c]
  float Wreg[4][32];
#pragma unroll
  for (int r = 0; r < 4; ++r)
#pragma unroll
    for (int q = 0; q < 8; ++q) {
      float4 v = *(const float4*)&Whh[(size_t)(lane + 64 * r) * Hn + 32 * w + 4 * q];
      Wreg[r][4 * q + 0] = v.x; Wreg[r][4 * q + 1] = v.y;
      Wreg[r][4 * q + 2] = v.z; Wreg[r][4 * q + 3] = v.w;
    }

  const int pw0 = PSTRIDE * lane + w;
  const float bias = bhh[ocol];

  float hv[32];
#pragma unroll
  for (int j = 0; j < 8; ++j)
    *(float4*)&hv[4 * j] = *(const float4*)&h0_b[32 * w + 4 * j];

  for (int c = 0; c < NCHUNK; ++c) {
    // acquire this chunk's xp (all producer slices)
    if (t == 0) wait_ge_n(wbase, nw, c + 1);
    __syncthreads();

    const int s0 = c * CHUNK;
    // fresh loads of the two slots the cross-chunk prefetch may have staled
    float xp_cur = xp_b[(size_t)s0 * Hn + ocol];
    float xp_n1  = xp_b[(size_t)(s0 + 1) * Hn + ocol];

    for (int ss = 0; ss < CHUNK; ++ss) {
      const int s = s0 + ss;
      // depth-2 prefetch: consumed two steps later (~1.2us of cover)
      float xp_n2 = (s + 2 < Sn) ? xp_b[(size_t)(s + 2) * Hn + ocol] : 0.0f;

      float a0 = 0.f, a1 = 0.f, a2 = 0.f, a3 = 0.f;
#pragma unroll
      for (int cc = 0; cc < 32; ++cc) {
        a0 += Wreg[0][cc] * hv[cc];
        a1 += Wreg[1][cc] * hv[cc];
        a2 += Wreg[2][cc] * hv[cc];
        a3 += Wreg[3][cc] * hv[cc];
      }
      float* pbuf = &part[(s & 1) * PBUF];
      pbuf[pw0       ] = a0;
      pbuf[pw0 +  576] = a1;
      pbuf[pw0 + 1152] = a2;
      pbuf[pw0 + 1728] = a3;

      asm volatile("s_waitcnt lgkmcnt(0)" ::: "memory");
      __builtin_amdgcn_s_barrier();
      __builtin_amdgcn_sched_barrier(0);

      const float* prow = &pbuf[PSTRIDE * ocol + 4 * hh];
      float r0 = prow[0], r1 = prow[1], r2 = prow[2], r3 = prow[3];
      float s4 = (r0 + r1) + (r2 + r3);
      float tot = s4 + __shfl_xor(s4, 32, 64);
      float hn = tanh_fast(tot + xp_cur + bias);
      if (lane < 32) {
        hbuf[ocol] = hn;
        y_b[(size_t)s * Hn + ocol] = hn;   // fire-and-forget global store
      }
      xp_cur = xp_n1;
      xp_n1 = xp_n2;

      __builtin_amdgcn_wave_barrier();     // keep reads after the write
#pragma unroll
      for (int j = 0; j < 8; ++j)
        *(float4*)&hv[4 * j] = *(const float4*)&hbuf[32 * w + 4 * j];
    }

    if (pub) publish(pub, (unsigned)(c + 1), t);
  }

  if (lane < 32) hfin_b[ocol] = hbuf[ocol];
}

// ---------------------------------------------------------------------------
// Projection worker: one block per (layer, batch, N-tile-range). Per chunk:
//   C[64, tiles] = A[64,256] * W[tiles,256]^T + bias
// 512 threads; K staged in 64-chunks, k ascending -> summation order
// identical to all prior rounds (absmax-stable).
// proj2 is split 4-way (1 tile/block) so its per-chunk latency (~10us) is
// far under the rec cadence (38.6us) -> proj2 never gates rec2 (round 5-7's
// hidden bottleneck: 1 serial block/batch at ~60us/chunk GATED the pipe).
// ---------------------------------------------------------------------------
__device__ void proj_body(const float* __restrict__ Ab,
                          const float* __restrict__ W,
                          const float* __restrict__ bias,
                          float* __restrict__ Cb,
                          unsigned* waitf, unsigned* pub,
                          int nt0, int nt1,
                          float* smem) {
  const int t = threadIdx.x;
  const int tx = t & 15;    // 4 cols each
  const int ty = t >> 4;    // 0..31, 2 rows each
  float (*As)[68] = (float(*)[68])smem;
  float (*Bs)[68] = (float(*)[68])(smem + 64 * 68);

  for (int c = 0; c < NCHUNK; ++c) {
    if (waitf) {
      if (t == 0) wait_ge_n(waitf, 1, c + 1);
      __syncthreads();
    }
    const float* A = Ab + (size_t)(c * CHUNK) * Hn;
    float* C = Cb + (size_t)(c * CHUNK) * Hn;

    for (int nt = nt0; nt < nt1; ++nt) {
      const int n0 = nt * 64;
      float acc[2][4] = {{0.f, 0.f, 0.f, 0.f}, {0.f, 0.f, 0.f, 0.f}};
      for (int kc = 0; kc < Hn; kc += 64) {
#pragma unroll
        for (int r = 0; r < 2; ++r) {
          int idx = t + 512 * r;           // 0..1023 -> 64 rows x 16 float4
          int mm = idx >> 4;
          int kk = (idx & 15) << 2;
          float4 av = *(const float4*)&A[(size_t)mm * Hn + kc + kk];
          As[kk + 0][mm] = av.x; As[kk + 1][mm] = av.y;
          As[kk + 2][mm] = av.z; As[kk + 3][mm] = av.w;
          float4 wv = *(const float4*)&W[(size_t)(n0 + mm) * Hn + kc + kk];
          Bs[kk + 0][mm] = wv.x; Bs[kk + 1][mm] = wv.y;
          Bs[kk + 2][mm] = wv.z; Bs[kk + 3][mm] = wv.w;
        }
        __syncthreads();
#pragma unroll
        for (int k = 0; k < 64; ++k) {
          float a0 = As[k][2 * ty], a1 = As[k][2 * ty + 1];
          float4 bv = *(const float4*)&Bs[k][tx << 2];
          acc[0][0] += a0 * bv.x; acc[0][1] += a0 * bv.y;
          acc[0][2] += a0 * bv.z; acc[0][3] += a0 * bv.w;
          acc[1][0] += a1 * bv.x; acc[1][1] += a1 * bv.y;
          acc[1][2] += a1 * bv.z; acc[1][3] += a1 * bv.w;
        }
        __syncthreads();
      }
      float4 bb = *(const float4*)&bias[n0 + (tx << 2)];
#pragma unroll
      for (int i = 0; i < 2; ++i) {
        float4 o;
        o.x = acc[i][0] + bb.x; o.y = acc[i][1] + bb.y;
        o.z = acc[i][2] + bb.z; o.w = acc[i][3] + bb.w;
        *(float4*)&C[(size_t)(2 * ty + i) * Hn + n0 + (tx << 2)] = o;
      }
    }

    if (pub) publish(pub, (unsigned)(c + 1), t);
  }
}

// ---------------------------------------------------------------------------
// Fused pipeline kernel. 256 blocks x 512 threads (one per CU):
//   [  0, 32): rec1, batch b      waits xp1[b] (2 flags), publishes y1[b]
//   [ 32, 64): rec2, batch b      waits xp2[b] (4 flags)
//   [ 64,128): proj1 (b, half j)  publishes xp1[b] half j
//   [128,256): proj2 (b, tile q)  waits y1[b], publishes xp2[b] quarter q
// xp2 overwrites xp1 in place in ws (proj2 writes chunk c only after rec1
// published chunk c, i.e. fully consumed it; rec1's c+1 prefetches are
// re-loaded fresh after its next acquire), so ws stays 64 MiB.
// rec2 overwrites y1[c] with y2[c] only after all proj2 tiles consumed
// y1[c] (ordered through the 4 xp2 flags).
// ---------------------------------------------------------------------------
__global__ __launch_bounds__(512) void fused(
    const float* __restrict__ x, const float* __restrict__ h0,
    const float* __restrict__ Wih, const float* __restrict__ Whh,
    const float* __restrict__ bih, const float* __restrict__ bhh,
    float* __restrict__ yout, float* __restrict__ fin,
    float* __restrict__ xpws) {
  __shared__ float smem[2 * 64 * 68];   // 34.8 KB; rec carves part+hbuf
  const int bid = blockIdx.x;

  if (bid < 32) {
    const int b = bid;
    rec_body(xpws + (size_t)b * Sn * Hn, Whh, bhh, h0 + (size_t)b * Hn,
             yout + (size_t)b * Sn * Hn, fin + (size_t)b * Hn,
             &g_flags[(0 * Bn + b) * FPAD], 2, &g_flags[(2 * Bn + b) * FPAD],
             smem, smem + 2 * PBUF);
  } else if (bid < 64) {
    const int b = bid - 32;
    rec_body(xpws + (size_t)b * Sn * Hn, Whh + Hn * Hn, bhh + Hn,
             h0 + (size_t)Bn * Hn + (size_t)b * Hn,
             yout + (size_t)b * Sn * Hn, fin + (size_t)Bn * Hn + (size_t)b * Hn,
             &g_flags[(3 * Bn + b) * FPAD], 4, nullptr,
             smem, smem + 2 * PBUF);
  } else if (bid < 128) {
    const int q = bid - 64;
    const int b = q & 31, j = q >> 5;      // half j: tiles 2j..2j+1
    proj_body(x + (size_t)b * Sn * Hn, Wih, bih, xpws + (size_t)b * Sn * Hn,
              nullptr, &g_flags[((0 + j) * Bn + b) * FPAD],
              2 * j, 2 * j + 2, smem);
  } else {
    const int q = bid - 128;
    const int b = q & 31, tq = q >> 5;     // quarter tq: tile tq
    proj_body(yout + (size_t)b * Sn * Hn, Wih + Hn * Hn, bih + Hn,
              xpws + (size_t)b * Sn * Hn,
              &g_flags[(2 * Bn + b) * FPAD],
              &g_flags[((3 + tq) * Bn + b) * FPAD],
              tq, tq + 1, smem);
  }
}

// ---------------------------------------------------------------------------
// Launch: zero flags, then the single fused pipeline kernel.
// ws needs Bn*Sn*Hn*4 = 64 MiB (xp buffer, shared by both layers in-place).
// ---------------------------------------------------------------------------
extern "C" void kernel_launch(void* const* d_in, const int* in_sizes, int n_in,
                              void* d_out, int out_size, void* d_ws, size_t ws_size,
                              hipStream_t stream) {
  const float* x   = (const float*)d_in[0];
  const float* h0  = (const float*)d_in[1];
  const float* Wih = (const float*)d_in[2];
  const float* Whh = (const float*)d_in[3];
  const float* bih = (const float*)d_in[4];
  const float* bhh = (const float*)d_in[5];

  float* out = (float*)d_out;
  float* yout = out;                              // [Bn,Sn,Hn]
  float* fin  = out + (size_t)Bn * Sn * Hn;       // [Ln,Bn,Hn]
  float* xpws = (float*)d_ws;                     // [Bn,Sn,Hn] scratch

  zero_flags_k<<<1, 256, 0, stream>>>();
  fused<<<256, 512, 0, stream>>>(x, h0, Wih, Whh, bih, bhh, yout, fin, xpws);
}

// Round 9
// 1813.285 us; speedup vs baseline: 1.2337x; 1.1341x over previous
//
#include <hip/hip_runtime.h>
#include <cstddef>

#define Bn 32
#define Sn 2048
#define Hn 256
#define Ln 2
#define CHUNK 64
#define NCHUNK (Sn / CHUNK)   // 32

#define PSTRIDE 9
#define PBUF (Hn * PSTRIDE)   // 2304 words per partial buffer

#define FPAD 32               // one flag per 128B line
#define NFL (5 * Bn)          // 1 y1 + 4 xp2-quarter flags per batch

// ---------------------------------------------------------------------------
// Pipeline flags (chunk-granular monotone counters), zeroed each launch.
//   slot (0,    b): y1[b] chunks done           (rec1 publishes)
//   slot (1..4, b): xp2[b] ready, N-quarter q   (proj2 tile-blocks publish)
// rec1 is flag-FREE on the consume side (xp1 fully materialized by the
// preceding proj_gemm kernel). rec2 consumes xp2 via sc1 loads -> its
// acquire is a pure poll, NO fence (r7-proven protocol, loads only).
// ---------------------------------------------------------------------------
__device__ unsigned g_flags[NFL * FPAD];

__global__ void zero_flags_k() {
  int i = threadIdx.x;
  if (i < NFL)
    __hip_atomic_store(&g_flags[i * FPAD], 0u, __ATOMIC_RELAXED,
                       __HIP_MEMORY_SCOPE_AGENT);
}

__device__ __forceinline__ float tanh_fast(float x) {
  // tanh(x) = 1 - 2/(exp(2x)+1); saturates correctly at +/-inf
  float e = __expf(2.0f * x);
  return 1.0f - 2.0f / (e + 1.0f);
}

// sc1 (device-scope) relaxed load: bypasses the non-coherent L2, reads the
// L3 coherence point. Lets the consumer skip the bulk-invalidate fence.
__device__ __forceinline__ float ldg_dev(const float* p) {
  return __hip_atomic_load(p, __ATOMIC_RELAXED, __HIP_MEMORY_SCOPE_AGENT);
}

// pure poll, no fence (consumer reads the data via sc1 loads)
__device__ __forceinline__ void poll_ge_n(unsigned* base, int n, unsigned tgt) {
  for (int q = 0; q < n; ++q) {
    unsigned* f = base + (size_t)q * Bn * FPAD;
    while (__hip_atomic_load(f, __ATOMIC_RELAXED, __HIP_MEMORY_SCOPE_AGENT) < tgt)
      __builtin_amdgcn_s_sleep(2);
  }
}

// poll + one acquire fence (consumer reads data via normal cached loads)
__device__ __forceinline__ void wait_fence(unsigned* f, unsigned tgt) {
  while (__hip_atomic_load(f, __ATOMIC_RELAXED, __HIP_MEMORY_SCOPE_AGENT) < tgt)
    __builtin_amdgcn_s_sleep(2);
  __threadfence();
}

// publisher: drain stores, barrier, t0 writes back dirty L2 + stores flag
__device__ __forceinline__ void publish(unsigned* f, unsigned val, int t) {
  asm volatile("s_waitcnt vmcnt(0)" ::: "memory");
  __syncthreads();
  if (t == 0) {
    __threadfence();
    __hip_atomic_store(f, val, __ATOMIC_RELAXED, __HIP_MEMORY_SCOPE_AGENT);
  }
}

// ---------------------------------------------------------------------------
// Original full-grid projection GEMM (round-0 proven, ~165us):
//   C[M,N] = A[M,K] * W[N,K]^T + bias, M=Bn*Sn, N=K=Hn. 256 thr, 64x64 tile.
// Runs as its OWN kernel before the pipeline -> rec1 needs no flags at all.
// ---------------------------------------------------------------------------
__global__ __launch_bounds__(256) void proj_gemm(
    const float* __restrict__ A,
    const float* __restrict__ W,
    const float* __restrict__ bias,
    float* __restrict__ C)
{
  __shared__ float As[64][68];
  __shared__ float Bs[64][68];
  const int tid = threadIdx.x;
  const int tx = tid & 15;
  const int ty = tid >> 4;
  const size_t m0 = (size_t)blockIdx.y * 64;
  const int n0 = blockIdx.x * 64;

  float acc[4][4];
#pragma unroll
  for (int i = 0; i < 4; ++i)
#pragma unroll
    for (int j = 0; j < 4; ++j) acc[i][j] = 0.0f;

  for (int kc = 0; kc < Hn; kc += 64) {
#pragma unroll
    for (int r = 0; r < 4; ++r) {
      int idx = tid + 256 * r;
      int mm = idx >> 4;
      int kk = (idx & 15) << 2;
      float4 av = *(const float4*)&A[(m0 + (size_t)mm) * Hn + kc + kk];
      As[kk + 0][mm] = av.x; As[kk + 1][mm] = av.y;
      As[kk + 2][mm] = av.z; As[kk + 3][mm] = av.w;
      float4 wv = *(const float4*)&W[(size_t)(n0 + mm) * Hn + kc + kk];
      Bs[kk + 0][mm] = wv.x; Bs[kk + 1][mm] = wv.y;
      Bs[kk + 2][mm] = wv.z; Bs[kk + 3][mm] = wv.w;
    }
    __syncthreads();
#pragma unroll
    for (int k = 0; k < 64; ++k) {
      float4 a = *(const float4*)&As[k][ty << 2];
      float4 b = *(const float4*)&Bs[k][tx << 2];
      float av4[4] = {a.x, a.y, a.z, a.w};
      float bv4[4] = {b.x, b.y, b.z, b.w};
#pragma unroll
      for (int i = 0; i < 4; ++i)
#pragma unroll
        for (int j = 0; j < 4; ++j)
          acc[i][j] += av4[i] * bv4[j];
    }
    __syncthreads();
  }

  float4 bv = *(const float4*)&bias[n0 + (tx << 2)];
  float badd[4] = {bv.x, bv.y, bv.z, bv.w};
#pragma unroll
  for (int i = 0; i < 4; ++i) {
    float4 o;
    o.x = acc[i][0] + badd[0];
    o.y = acc[i][1] + badd[1];
    o.z = acc[i][2] + badd[2];
    o.w = acc[i][3] + badd[3];
    *(float4*)&C[(m0 + (size_t)((ty << 2) + i)) * Hn + n0 + (tx << 2)] = o;
  }
}

// ---------------------------------------------------------------------------
// Recurrence body — EXACT round-2 step structure (603 ns/step standalone).
// Template SC1: rec2 reads xp via sc1 loads (acquire = pure poll, no fence);
// rec1 reads xp via normal cached loads and has NO acquire at all.
//   wave w owns k-chunk [32w,32w+32) and outputs [32w,32w+32)
//   partials at part[9*o + w]: write bank (9l+w)%32 -> 2-way only (free)
//   single raw s_barrier per step, partials double-buffered on (s&1)
//   reduce: lane sums 4 of 8 slots + one shfl_xor(32)
//   h exchange via hbuf LDS (wave-local readback, wave_barrier only)
// ---------------------------------------------------------------------------
template <bool SC1>
__device__ void rec_body(const float* __restrict__ xp_b,
                         const float* __restrict__ Whh,
                         const float* __restrict__ bhh,
                         const float* __restrict__ h0_b,
                         float* __restrict__ y_b,
                         float* __restrict__ hfin_b,
                         unsigned* wbase, int nw, unsigned* pub,
                         float* part, float* hbuf) {
  const int t = threadIdx.x;
  const int lane = t & 63;
  const int w = t >> 6;                   // 0..7
  const int ocol = 32 * w + (lane & 31);  // output this lane reduces
  const int hh = lane >> 5;               // which half of the 8 slots

  // Wreg[r][c] = Whh[lane + 64r][32w + c]
  float Wreg[4][32];
#pragma unroll
  for (int r = 0; r < 4; ++r)
#pragma unroll
    for (int q = 0; q < 8; ++q) {
      float4 v = *(const float4*)&Whh[(size_t)(lane + 64 * r) * Hn + 32 * w + 4 * q];
      Wreg[r][4 * q + 0] = v.x; Wreg[r][4 * q + 1] = v.y;
      Wreg[r][4 * q + 2] = v.z; Wreg[r][4 * q + 3] = v.w;
    }

  const int pw0 = PSTRIDE * lane + w;
  const float bias = bhh[ocol];

  float hv[32];
#pragma unroll
  for (int j = 0; j < 8; ++j)
    *(float4*)&hv[4 * j] = *(const float4*)&h0_b[32 * w + 4 * j];

  float xp_cur = 0.0f, xp_n1 = 0.0f;
  if (!SC1) {  // xp fully materialized: start the rolling prefetch now
    xp_cur = xp_b[ocol];
    xp_n1  = xp_b[(size_t)1 * Hn + ocol];
  }

  for (int c = 0; c < NCHUNK; ++c) {
    const int s0 = c * CHUNK;
    if (SC1) {
      // acquire this chunk's xp quarters: pure poll, NO fence (sc1 reads)
      if (t == 0) poll_ge_n(wbase, nw, c + 1);
      __syncthreads();
      // reload the two slots the cross-chunk prefetch may have staled
      xp_cur = ldg_dev(&xp_b[(size_t)s0 * Hn + ocol]);
      xp_n1  = ldg_dev(&xp_b[(size_t)(s0 + 1) * Hn + ocol]);
    }

    for (int ss = 0; ss < CHUNK; ++ss) {
      const int s = s0 + ss;
      // depth-2 prefetch: consumed two steps later (~1.2us of cover)
      float xp_n2 = 0.0f;
      if (s + 2 < Sn)
        xp_n2 = SC1 ? ldg_dev(&xp_b[(size_t)(s + 2) * Hn + ocol])
                    : xp_b[(size_t)(s + 2) * Hn + ocol];

      float a0 = 0.f, a1 = 0.f, a2 = 0.f, a3 = 0.f;
#pragma unroll
      for (int cc = 0; cc < 32; ++cc) {
        a0 += Wreg[0][cc] * hv[cc];
        a1 += Wreg[1][cc] * hv[cc];
        a2 += Wreg[2][cc] * hv[cc];
        a3 += Wreg[3][cc] * hv[cc];
      }
      float* pbuf = &part[(s & 1) * PBUF];
      pbuf[pw0       ] = a0;
      pbuf[pw0 +  576] = a1;
      pbuf[pw0 + 1152] = a2;
      pbuf[pw0 + 1728] = a3;

      asm volatile("s_waitcnt lgkmcnt(0)" ::: "memory");
      __builtin_amdgcn_s_barrier();
      __builtin_amdgcn_sched_barrier(0);

      const float* prow = &pbuf[PSTRIDE * ocol + 4 * hh];
      float r0 = prow[0], r1 = prow[1], r2 = prow[2], r3 = prow[3];
      float s4 = (r0 + r1) + (r2 + r3);
      float tot = s4 + __shfl_xor(s4, 32, 64);
      float hn = tanh_fast(tot + xp_cur + bias);
      if (lane < 32) {
        hbuf[ocol] = hn;
        y_b[(size_t)s * Hn + ocol] = hn;   // fire-and-forget global store
      }
      xp_cur = xp_n1;
      xp_n1 = xp_n2;

      __builtin_amdgcn_wave_barrier();     // keep reads after the write
#pragma unroll
      for (int j = 0; j < 8; ++j)
        *(float4*)&hv[4 * j] = *(const float4*)&hbuf[32 * w + 4 * j];
    }

    if (pub) publish(pub, (unsigned)(c + 1), t);
  }

  if (lane < 32) hfin_b[ocol] = hbuf[ocol];
}

// ---------------------------------------------------------------------------
// proj2 worker: one block per (batch, N-tile). Per chunk c:
//   C[64,64] = A[64,256] * W[64,256]^T + bias, k ascending (absmax-stable).
// Normal cached loads/stores; acquire with fence (reads rec1's y1), publish
// with writeback (rec2 reads xp2 from L3 via sc1). ~10us work / 38.6us
// cadence -> never gates, fences harmless here.
// ---------------------------------------------------------------------------
__device__ void proj2_body(const float* __restrict__ Ab,
                           const float* __restrict__ W,
                           const float* __restrict__ bias,
                           float* __restrict__ Cb,
                           unsigned* waitf, unsigned* pub, int nt,
                           float* smem) {
  const int t = threadIdx.x;
  const int tx = t & 15;    // 4 cols each
  const int ty = t >> 4;    // 0..31, 2 rows each
  float (*As)[68] = (float(*)[68])smem;
  float (*Bs)[68] = (float(*)[68])(smem + 64 * 68);
  const int n0 = nt * 64;

  for (int c = 0; c < NCHUNK; ++c) {
    if (t == 0) wait_fence(waitf, c + 1);
    __syncthreads();

    const float* A = Ab + (size_t)(c * CHUNK) * Hn;
    float* C = Cb + (size_t)(c * CHUNK) * Hn;

    float acc[2][4] = {{0.f, 0.f, 0.f, 0.f}, {0.f, 0.f, 0.f, 0.f}};
    for (int kc = 0; kc < Hn; kc += 64) {
#pragma unroll
      for (int r = 0; r < 2; ++r) {
        int idx = t + 512 * r;             // 0..1023 -> 64 rows x 16 float4
        int mm = idx >> 4;
        int kk = (idx & 15) << 2;
        float4 av = *(const float4*)&A[(size_t)mm * Hn + kc + kk];
        As[kk + 0][mm] = av.x; As[kk + 1][mm] = av.y;
        As[kk + 2][mm] = av.z; As[kk + 3][mm] = av.w;
        float4 wv = *(const float4*)&W[(size_t)(n0 + mm) * Hn + kc + kk];
        Bs[kk + 0][mm] = wv.x; Bs[kk + 1][mm] = wv.y;
        Bs[kk + 2][mm] = wv.z; Bs[kk + 3][mm] = wv.w;
      }
      __syncthreads();
#pragma unroll
      for (int k = 0; k < 64; ++k) {
        float a0 = As[k][2 * ty], a1 = As[k][2 * ty + 1];
        float4 bv = *(const float4*)&Bs[k][tx << 2];
        acc[0][0] += a0 * bv.x; acc[0][1] += a0 * bv.y;
        acc[0][2] += a0 * bv.z; acc[0][3] += a0 * bv.w;
        acc[1][0] += a1 * bv.x; acc[1][1] += a1 * bv.y;
        acc[1][2] += a1 * bv.z; acc[1][3] += a1 * bv.w;
      }
      __syncthreads();
    }
    float4 bb = *(const float4*)&bias[n0 + (tx << 2)];
#pragma unroll
    for (int i = 0; i < 2; ++i) {
      float4 o;
      o.x = acc[i][0] + bb.x; o.y = acc[i][1] + bb.y;
      o.z = acc[i][2] + bb.z; o.w = acc[i][3] + bb.w;
      *(float4*)&C[(size_t)(2 * ty + i) * Hn + n0 + (tx << 2)] = o;
    }

    publish(pub, (unsigned)(c + 1), t);
  }
}

// ---------------------------------------------------------------------------
// Fused pipeline kernel. 192 blocks x 512 threads:
//   [  0, 32): rec1, batch b      NO acquire; publishes y1[b]
//   [ 32, 64): rec2, batch b      pure-poll acquire of 4 xp2 flags (sc1 xp)
//   [ 64,192): proj2 (b, tile q)  waits y1[b] (+fence), publishes xp2[b][q]
// xp2 overwrites xp1 in place (proj2 writes chunk c only after rec1
// published c = fully consumed it; rec1's 2-slot lookahead into c+1 is a
// disjoint region), so ws stays 64 MiB.
// ---------------------------------------------------------------------------
__global__ __launch_bounds__(512) void fused(
    const float* __restrict__ h0,
    const float* __restrict__ Wih, const float* __restrict__ Whh,
    const float* __restrict__ bih, const float* __restrict__ bhh,
    float* __restrict__ yout, float* __restrict__ fin,
    float* __restrict__ xpws) {
  __shared__ float smem[2 * 64 * 68];   // 34.8 KB; rec carves part+hbuf
  const int bid = blockIdx.x;

  if (bid < 32) {
    const int b = bid;
    rec_body<false>(xpws + (size_t)b * Sn * Hn, Whh, bhh,
                    h0 + (size_t)b * Hn,
                    yout + (size_t)b * Sn * Hn, fin + (size_t)b * Hn,
                    nullptr, 0, &g_flags[(0 * Bn + b) * FPAD],
                    smem, smem + 2 * PBUF);
  } else if (bid < 64) {
    const int b = bid - 32;
    rec_body<true>(xpws + (size_t)b * Sn * Hn, Whh + Hn * Hn, bhh + Hn,
                   h0 + (size_t)Bn * Hn + (size_t)b * Hn,
                   yout + (size_t)b * Sn * Hn,
                   fin + (size_t)Bn * Hn + (size_t)b * Hn,
                   &g_flags[(1 * Bn + b) * FPAD], 4, nullptr,
                   smem, smem + 2 * PBUF);
  } else {
    const int q = bid - 64;
    const int b = q & 31, tq = q >> 5;    // tile tq in 0..3
    proj2_body(yout + (size_t)b * Sn * Hn, Wih + Hn * Hn, bih + Hn,
               xpws + (size_t)b * Sn * Hn,
               &g_flags[(0 * Bn + b) * FPAD],
               &g_flags[((1 + tq) * Bn + b) * FPAD],
               tq, smem);
  }
}

// ---------------------------------------------------------------------------
// Launch: zero flags, full-grid proj1 (xp1 fully materialized, no flags),
// then the rec1 | proj2 | rec2 pipeline kernel.
// ws needs Bn*Sn*Hn*4 = 64 MiB (xp buffer, shared by both layers in-place).
// ---------------------------------------------------------------------------
extern "C" void kernel_launch(void* const* d_in, const int* in_sizes, int n_in,
                              void* d_out, int out_size, void* d_ws, size_t ws_size,
                              hipStream_t stream) {
  const float* x   = (const float*)d_in[0];
  const float* h0  = (const float*)d_in[1];
  const float* Wih = (const float*)d_in[2];
  const float* Whh = (const float*)d_in[3];
  const float* bih = (const float*)d_in[4];
  const float* bhh = (const float*)d_in[5];

  float* out = (float*)d_out;
  float* yout = out;                              // [Bn,Sn,Hn]
  float* fin  = out + (size_t)Bn * Sn * Hn;       // [Ln,Bn,Hn]
  float* xpws = (float*)d_ws;                     // [Bn,Sn,Hn] scratch

  zero_flags_k<<<1, 256, 0, stream>>>();

  dim3 pgrid(Hn / 64, (Bn * Sn) / 64);
  proj_gemm<<<pgrid, 256, 0, stream>>>(x, Wih, bih, xpws);

  fused<<<192, 512, 0, stream>>>(h0, Wih, Whh, bih, bhh, yout, fin, xpws);
}

// Round 10
// 1792.337 us; speedup vs baseline: 1.2481x; 1.0117x over previous
//
#include <hip/hip_runtime.h>
#include <cstddef>

#define Bn 32
#define Sn 2048
#define Hn 256
#define Ln 2
#define CHUNK 64
#define NCHUNK (Sn / CHUNK)   // 32

#define PSTRIDE 9
#define PBUF (Hn * PSTRIDE)   // 2304 words per partial buffer

#define FPAD 32               // one flag per 128B line
#define NFL (5 * Bn)          // 2 xp1-half + 1 y1 + 2 xp2-half per batch

// ---------------------------------------------------------------------------
// ZERO-FENCE pipeline. All cross-block data is made L3-visible by the
// PRODUCER (relaxed agent-scope = sc1 write-through stores); consumers read
// normal-cached EXCEPT where their XCD L2 can provably hold a stale copy
// (rec2's xp: same in-place addresses as co-XCD rec1's cached xp1 lines;
// both recs' 2 boundary rows: their own pre-flag cross-chunk prefetches).
// Those go through sc1 loads (L2 bypass). No __threadfence in the binary ->
// no bulk L2 invalidations -> rec xp prefetches survive (r5/r6/r9: time
// tracked total fence rate monotonically; this removes the last of them).
// Flag slots (chunk-granular monotone counters):
//   (0..1,b): xp1[b] half j ready   (proj1 half-blocks)
//   (2,   b): y1[b] done            (rec1)
//   (3..4,b): xp2[b] half j ready   (proj2 half-blocks)
// ---------------------------------------------------------------------------
__device__ unsigned g_flags[NFL * FPAD];

__global__ void zero_flags_k() {
  int i = threadIdx.x;
  if (i < NFL)
    __hip_atomic_store(&g_flags[i * FPAD], 0u, __ATOMIC_RELAXED,
                       __HIP_MEMORY_SCOPE_AGENT);
}

__device__ __forceinline__ float tanh_fast(float x) {
  // tanh(x) = 1 - 2/(exp(2x)+1); saturates correctly at +/-inf
  float e = __expf(2.0f * x);
  return 1.0f - 2.0f / (e + 1.0f);
}

// sc1 (agent-scope) relaxed data ops: read/write the L3 coherence point.
__device__ __forceinline__ float ldg_dev(const float* p) {
  return __hip_atomic_load(p, __ATOMIC_RELAXED, __HIP_MEMORY_SCOPE_AGENT);
}
__device__ __forceinline__ void stg_dev(float* p, float v) {
  __hip_atomic_store(p, v, __ATOMIC_RELAXED, __HIP_MEMORY_SCOPE_AGENT);
}

// pure poll over n flags (stride Bn*FPAD apart). NO fence.
__device__ __forceinline__ void poll_ge_n(unsigned* base, int n, unsigned tgt) {
  for (int q = 0; q < n; ++q) {
    unsigned* f = base + (size_t)q * Bn * FPAD;
    while (__hip_atomic_load(f, __ATOMIC_RELAXED, __HIP_MEMORY_SCOPE_AGENT) < tgt)
      __builtin_amdgcn_s_sleep(2);
  }
}

// publisher: every wave drains its (sc1, write-through) stores to the
// coherence point, barrier, then t0 stores the flag. NO fence.
__device__ __forceinline__ void publish(unsigned* f, unsigned val, int t) {
  asm volatile("s_waitcnt vmcnt(0)" ::: "memory");
  __syncthreads();
  if (t == 0)
    __hip_atomic_store(f, val, __ATOMIC_RELAXED, __HIP_MEMORY_SCOPE_AGENT);
}

// ---------------------------------------------------------------------------
// Recurrence body — EXACT round-2 step structure (603 ns/step standalone).
//   wave w owns k-chunk [32w,32w+32) and outputs [32w,32w+32)
//   partials at part[9*o + w]: write bank (9l+w)%32 -> 2-way only (free)
//   single raw s_barrier per step, partials double-buffered on (s&1)
//   reduce: lane sums 4 of 8 slots + one shfl_xor(32)
//   h exchange via hbuf LDS (wave-local readback, wave_barrier only)
// XP_SC1: rec2=true (ALL xp reads sc1 -- in-place xp2 aliases xp1 lines
// cached by co-XCD rec1). rec1=false (steady reads normal cached; only the
// 2 boundary rows -- its own pre-flag prefetch targets -- reload via sc1).
// Y_SC1: rec1=true (y1 consumed cross-XCD by proj2), rec2=false (final out).
// ---------------------------------------------------------------------------
template <bool XP_SC1, bool Y_SC1>
__device__ void rec_body(const float* __restrict__ xp_b,
                         const float* __restrict__ Whh,
                         const float* __restrict__ bhh,
                         const float* __restrict__ h0_b,
                         float* __restrict__ y_b,
                         float* __restrict__ hfin_b,
                         unsigned* wbase, int nw, unsigned* pub,
                         float* part, float* hbuf) {
  const int t = threadIdx.x;
  const int lane = t & 63;
  const int w = t >> 6;                   // 0..7
  const int ocol = 32 * w + (lane & 31);  // output this lane reduces
  const int hh = lane >> 5;               // which half of the 8 slots

  // Wreg[r][c] = Whh[lane + 64r][32w + c]
  float Wreg[4][32];
#pragma unroll
  for (int r = 0; r < 4; ++r)
#pragma unroll
    for (int q = 0; q < 8; ++q) {
      float4 v = *(const float4*)&Whh[(size_t)(lane + 64 * r) * Hn + 32 * w + 4 * q];
      Wreg[r][4 * q + 0] = v.x; Wreg[r][4 * q + 1] = v.y;
      Wreg[r][4 * q + 2] = v.z; Wreg[r][4 * q + 3] = v.w;
    }

  const int pw0 = PSTRIDE * lane + w;
  const float bias = bhh[ocol];

  float hv[32];
#pragma unroll
  for (int j = 0; j < 8; ++j)
    *(float4*)&hv[4 * j] = *(const float4*)&h0_b[32 * w + 4 * j];

  for (int c = 0; c < NCHUNK; ++c) {
    // acquire this chunk's xp halves: pure poll, no fence
    if (t == 0) poll_ge_n(wbase, nw, c + 1);
    __syncthreads();

    const int s0 = c * CHUNK;
    // sc1 reload of the two rows our pre-flag cross-chunk prefetch touched
    // (those lines may be stale in this XCD's L2)
    float xp_cur = ldg_dev(&xp_b[(size_t)s0 * Hn + ocol]);
    float xp_n1  = ldg_dev(&xp_b[(size_t)(s0 + 1) * Hn + ocol]);

    for (int ss = 0; ss < CHUNK; ++ss) {
      const int s = s0 + ss;
      // depth-2 prefetch: consumed two steps later (~1.2us of cover)
      float xp_n2 = 0.0f;
      if (s + 2 < Sn)
        xp_n2 = XP_SC1 ? ldg_dev(&xp_b[(size_t)(s + 2) * Hn + ocol])
                       : xp_b[(size_t)(s + 2) * Hn + ocol];

      float a0 = 0.f, a1 = 0.f, a2 = 0.f, a3 = 0.f;
#pragma unroll
      for (int cc = 0; cc < 32; ++cc) {
        a0 += Wreg[0][cc] * hv[cc];
        a1 += Wreg[1][cc] * hv[cc];
        a2 += Wreg[2][cc] * hv[cc];
        a3 += Wreg[3][cc] * hv[cc];
      }
      float* pbuf = &part[(s & 1) * PBUF];
      pbuf[pw0       ] = a0;
      pbuf[pw0 +  576] = a1;
      pbuf[pw0 + 1152] = a2;
      pbuf[pw0 + 1728] = a3;

      asm volatile("s_waitcnt lgkmcnt(0)" ::: "memory");
      __builtin_amdgcn_s_barrier();
      __builtin_amdgcn_sched_barrier(0);

      const float* prow = &pbuf[PSTRIDE * ocol + 4 * hh];
      float r0 = prow[0], r1 = prow[1], r2 = prow[2], r3 = prow[3];
      float s4 = (r0 + r1) + (r2 + r3);
      float tot = s4 + __shfl_xor(s4, 32, 64);
      float hn = tanh_fast(tot + xp_cur + bias);
      if (lane < 32) {
        hbuf[ocol] = hn;
        if (Y_SC1) stg_dev(&y_b[(size_t)s * Hn + ocol], hn);  // L3 write-through
        else       y_b[(size_t)s * Hn + ocol] = hn;           // final output
      }
      xp_cur = xp_n1;
      xp_n1 = xp_n2;

      __builtin_amdgcn_wave_barrier();     // keep reads after the write
#pragma unroll
      for (int j = 0; j < 8; ++j)
        *(float4*)&hv[4 * j] = *(const float4*)&hbuf[32 * w + 4 * j];
    }

    if (pub) publish(pub, (unsigned)(c + 1), t);
  }

  if (lane < 32) hfin_b[ocol] = hbuf[ocol];
}

// ---------------------------------------------------------------------------
// Projection worker: one block per (layer, batch, N-half). Per chunk:
//   C[64, 2 tiles of 64] = A[64,256] * W[.,256]^T + bias
// k ascending, layout identical to all prior rounds (absmax-stable).
// A,W: normal cached loads (A is a single-read stream first touched after
// the flag; producer wrote it through to L3 -> no stale-L2 hazard).
// C (xp): sc1 scalar stores (write-through; consumed cross-XCD by rec).
// 2 blocks/batch: ~20us/chunk < 38.6us rec cadence -> never gates (r8).
// ---------------------------------------------------------------------------
__device__ void proj_body(const float* __restrict__ Ab,
                          const float* __restrict__ W,
                          const float* __restrict__ bias,
                          float* __restrict__ Cb,
                          unsigned* waitf, unsigned* pub,
                          int nt0, int nt1,
                          float* smem) {
  const int t = threadIdx.x;
  const int tx = t & 15;    // 4 cols each
  const int ty = t >> 4;    // 0..31, 2 rows each
  float (*As)[68] = (float(*)[68])smem;
  float (*Bs)[68] = (float(*)[68])(smem + 64 * 68);

  for (int c = 0; c < NCHUNK; ++c) {
    if (waitf) {
      if (t == 0) poll_ge_n(waitf, 1, c + 1);
      __syncthreads();
    }
    const float* A = Ab + (size_t)(c * CHUNK) * Hn;
    float* C = Cb + (size_t)(c * CHUNK) * Hn;

    for (int nt = nt0; nt < nt1; ++nt) {
      const int n0 = nt * 64;
      float acc[2][4] = {{0.f, 0.f, 0.f, 0.f}, {0.f, 0.f, 0.f, 0.f}};
      for (int kc = 0; kc < Hn; kc += 64) {
#pragma unroll
        for (int r = 0; r < 2; ++r) {
          int idx = t + 512 * r;           // 0..1023 -> 64 rows x 16 float4
          int mm = idx >> 4;
          int kk = (idx & 15) << 2;
          float4 av = *(const float4*)&A[(size_t)mm * Hn + kc + kk];
          As[kk + 0][mm] = av.x; As[kk + 1][mm] = av.y;
          As[kk + 2][mm] = av.z; As[kk + 3][mm] = av.w;
          float4 wv = *(const float4*)&W[(size_t)(n0 + mm) * Hn + kc + kk];
          Bs[kk + 0][mm] = wv.x; Bs[kk + 1][mm] = wv.y;
          Bs[kk + 2][mm] = wv.z; Bs[kk + 3][mm] = wv.w;
        }
        __syncthreads();
#pragma unroll
        for (int k = 0; k < 64; ++k) {
          float a0 = As[k][2 * ty], a1 = As[k][2 * ty + 1];
          float4 bv = *(const float4*)&Bs[k][tx << 2];
          acc[0][0] += a0 * bv.x; acc[0][1] += a0 * bv.y;
          acc[0][2] += a0 * bv.z; acc[0][3] += a0 * bv.w;
          acc[1][0] += a1 * bv.x; acc[1][1] += a1 * bv.y;
          acc[1][2] += a1 * bv.z; acc[1][3] += a1 * bv.w;
        }
        __syncthreads();
      }
      float4 bb = *(const float4*)&bias[n0 + (tx << 2)];
#pragma unroll
      for (int i = 0; i < 2; ++i) {
        float* cp = &C[(size_t)(2 * ty + i) * Hn + n0 + (tx << 2)];
        stg_dev(cp + 0, acc[i][0] + bb.x);
        stg_dev(cp + 1, acc[i][1] + bb.y);
        stg_dev(cp + 2, acc[i][2] + bb.z);
        stg_dev(cp + 3, acc[i][3] + bb.w);
      }
    }

    publish(pub, (unsigned)(c + 1), t);
  }
}

// ---------------------------------------------------------------------------
// Fused pipeline kernel. 192 blocks x 512 threads:
//   [  0, 32): rec1, batch b      polls xp1[b] (2 flags), publishes y1[b]
//   [ 32, 64): rec2, batch b      polls xp2[b] (2 flags)
//   [ 64,128): proj1 (b, half j)  no wait; publishes xp1[b] half j
//   [128,192): proj2 (b, half j)  polls y1[b]; publishes xp2[b] half j
// In-place xp reuse is flag-ordered: proj1[c] -> rec1[c] -> (y1 flag) ->
// proj2[c] -> rec2[c]; proj2 writes chunk c only after rec1 fully consumed
// it, and rec1's 2-row lookahead into c+1 targets a disjoint region.
// ---------------------------------------------------------------------------
__global__ __launch_bounds__(512) void fused(
    const float* __restrict__ x, const float* __restrict__ h0,
    const float* __restrict__ Wih, const float* __restrict__ Whh,
    const float* __restrict__ bih, const float* __restrict__ bhh,
    float* __restrict__ yout, float* __restrict__ fin,
    float* __restrict__ xpws) {
  __shared__ float smem[2 * 64 * 68];   // 34.8 KB; rec carves part+hbuf
  const int bid = blockIdx.x;

  if (bid < 32) {
    const int b = bid;
    rec_body<false, true>(xpws + (size_t)b * Sn * Hn, Whh, bhh,
                          h0 + (size_t)b * Hn,
                          yout + (size_t)b * Sn * Hn, fin + (size_t)b * Hn,
                          &g_flags[(0 * Bn + b) * FPAD], 2,
                          &g_flags[(2 * Bn + b) * FPAD],
                          smem, smem + 2 * PBUF);
  } else if (bid < 64) {
    const int b = bid - 32;
    rec_body<true, false>(xpws + (size_t)b * Sn * Hn, Whh + Hn * Hn, bhh + Hn,
                          h0 + (size_t)Bn * Hn + (size_t)b * Hn,
                          yout + (size_t)b * Sn * Hn,
                          fin + (size_t)Bn * Hn + (size_t)b * Hn,
                          &g_flags[(3 * Bn + b) * FPAD], 2, nullptr,
                          smem, smem + 2 * PBUF);
  } else if (bid < 128) {
    const int q = bid - 64;
    const int b = q & 31, j = q >> 5;    // half j: tiles 2j..2j+1
    proj_body(x + (size_t)b * Sn * Hn, Wih, bih, xpws + (size_t)b * Sn * Hn,
              nullptr, &g_flags[((0 + j) * Bn + b) * FPAD],
              2 * j, 2 * j + 2, smem);
  } else {
    const int q = bid - 128;
    const int b = q & 31, j = q >> 5;    // half j: tiles 2j..2j+1
    proj_body(yout + (size_t)b * Sn * Hn, Wih + Hn * Hn, bih + Hn,
              xpws + (size_t)b * Sn * Hn,
              &g_flags[(2 * Bn + b) * FPAD],
              &g_flags[((3 + j) * Bn + b) * FPAD],
              2 * j, 2 * j + 2, smem);
  }
}

// ---------------------------------------------------------------------------
// Launch: zero flags, then the single fully-pipelined kernel.
// ws needs Bn*Sn*Hn*4 = 64 MiB (xp buffer, shared by both layers in-place).
// ---------------------------------------------------------------------------
extern "C" void kernel_launch(void* const* d_in, const int* in_sizes, int n_in,
                              void* d_out, int out_size, void* d_ws, size_t ws_size,
                              hipStream_t stream) {
  const float* x   = (const float*)d_in[0];
  const float* h0  = (const float*)d_in[1];
  const float* Wih = (const float*)d_in[2];
  const float* Whh = (const float*)d_in[3];
  const float* bih = (const float*)d_in[4];
  const float* bhh = (const float*)d_in[5];

  float* out = (float*)d_out;
  float* yout = out;                              // [Bn,Sn,Hn]
  float* fin  = out + (size_t)Bn * Sn * Hn;       // [Ln,Bn,Hn]
  float* xpws = (float*)d_ws;                     // [Bn,Sn,Hn] scratch

  zero_flags_k<<<1, 256, 0, stream>>>();
  fused<<<192, 512, 0, stream>>>(x, h0, Wih, Whh, bih, bhh, yout, fin, xpws);
}

// Round 11
// 1757.093 us; speedup vs baseline: 1.2732x; 1.0201x over previous
//
#include <hip/hip_runtime.h>
#include <cstddef>

#define Bn 32
#define Sn 2048
#define Hn 256
#define Ln 2
#define CHUNK 64
#define NCHUNK (Sn / CHUNK)   // 32

#define PSTR 10
#define PBUF (Hn * PSTR)      // 2560 words per partial buffer

#define FPAD 32               // one flag per 128B line
#define NFL (5 * Bn)          // 2 xp1-half + 1 y1 + 2 xp2-half per batch

typedef float f32x2 __attribute__((ext_vector_type(2)));

// ---------------------------------------------------------------------------
// ZERO-FENCE pipeline (r10-proven): producers make cross-block data
// L3-visible with relaxed agent-scope (sc1, write-through) stores; consumers
// read normal-cached except where their XCD L2 can provably hold a stale
// copy (rec2's xp: in-place aliases of co-XCD rec1's cached xp1 lines; both
// recs' 2 boundary rows: their own pre-flag cross-chunk prefetch targets).
// No __threadfence in the binary -> no bulk L2 invalidations.
// Flag slots (chunk-granular monotone counters):
//   (0..1,b): xp1[b] half j ready   (proj1 half-blocks)
//   (2,   b): y1[b] done            (rec1)
//   (3..4,b): xp2[b] half j ready   (proj2 half-blocks)
// ---------------------------------------------------------------------------
__device__ unsigned g_flags[NFL * FPAD];

__global__ void zero_flags_k() {
  int i = threadIdx.x;
  if (i < NFL)
    __hip_atomic_store(&g_flags[i * FPAD], 0u, __ATOMIC_RELAXED,
                       __HIP_MEMORY_SCOPE_AGENT);
}

__device__ __forceinline__ float tanh_fast(float x) {
  // tanh(x) = 1 - 2/(exp(2x)+1); saturates correctly at +/-inf
  float e = __expf(2.0f * x);
  return 1.0f - 2.0f / (e + 1.0f);
}

// sc1 (agent-scope) relaxed data ops: read/write the L3 coherence point.
__device__ __forceinline__ float ldg_dev(const float* p) {
  return __hip_atomic_load(p, __ATOMIC_RELAXED, __HIP_MEMORY_SCOPE_AGENT);
}
__device__ __forceinline__ void stg_dev(float* p, float v) {
  __hip_atomic_store(p, v, __ATOMIC_RELAXED, __HIP_MEMORY_SCOPE_AGENT);
}

// pure poll over n flags (stride Bn*FPAD apart). NO fence.
__device__ __forceinline__ void poll_ge_n(unsigned* base, int n, unsigned tgt) {
  for (int q = 0; q < n; ++q) {
    unsigned* f = base + (size_t)q * Bn * FPAD;
    while (__hip_atomic_load(f, __ATOMIC_RELAXED, __HIP_MEMORY_SCOPE_AGENT) < tgt)
      __builtin_amdgcn_s_sleep(2);
  }
}

// publisher: every wave drains its (sc1 write-through) stores, barrier,
// then t0 stores the flag. NO fence.
__device__ __forceinline__ void publish(unsigned* f, unsigned val, int t) {
  asm volatile("s_waitcnt vmcnt(0)" ::: "memory");
  __syncthreads();
  if (t == 0)
    __hip_atomic_store(f, val, __ATOMIC_RELAXED, __HIP_MEMORY_SCOPE_AGENT);
}

// ---------------------------------------------------------------------------
// Recurrence body — pk_fma form (r3/r4-validated numerics) + r2's hbuf
// h-exchange + r10 pipeline wrappers.
//   wave w owns k-chunk [32w,32w+32) and outputs [32w,32w+32)
//   FMA: 64 v_pk_fma_f32/lane (halves the 512-cyc/SIMD scalar issue floor)
//   partials slot-major stride 10, slot = w ^ ((lane>>3)&3):
//     write bank (10l + slot)%32 worst 2-way; read 8B-aligned b64, 2-way
//   reduce: EVERY lane sums all 8 slots (4xb64 + pk adds) -> NO shfl
//     (removes the ~120-cyc ds_permute from the serial chain)
//   single raw s_barrier/step, partials double-buffered on (s&1)
// AGPR fix attempt: amdgpu_waves_per_eu(2,2) pins 2 waves/EU -> full
// 256-VGPR budget, so W should stay in ArchVGPRs (r3/r4: allocator parked
// W in AGPRs -> per-use accvgpr_read tax ate the pk gain). Discriminator:
// VGPR_Count >= 150 means it worked.
// ---------------------------------------------------------------------------
template <bool XP_SC1, bool Y_SC1>
__device__ void rec_body(const float* __restrict__ xp_b,
                         const float* __restrict__ Whh,
                         const float* __restrict__ bhh,
                         const float* __restrict__ h0_b,
                         float* __restrict__ y_b,
                         float* __restrict__ hfin_b,
                         unsigned* wbase, int nw, unsigned* pub,
                         float* part, float* hbuf) {
  const int t = threadIdx.x;
  const int lane = t & 63;
  const int w = t >> 6;                   // 0..7
  const int ocol = 32 * w + (lane & 31);  // output this lane reduces

  // Wreg[r][c2] = (Whh[lane+64r][32w+2c2], Whh[lane+64r][32w+2c2+1])
  f32x2 Wreg[4][16];
#pragma unroll
  for (int r = 0; r < 4; ++r)
#pragma unroll
    for (int q = 0; q < 8; ++q) {
      float4 v = *(const float4*)&Whh[(size_t)(lane + 64 * r) * Hn + 32 * w + 4 * q];
      Wreg[r][2 * q + 0] = f32x2{v.x, v.y};
      Wreg[r][2 * q + 1] = f32x2{v.z, v.w};
    }
  // pin W pairs to the ArchVGPR class (anti-AGPR insurance; zero runtime)
#pragma unroll
  for (int r = 0; r < 4; ++r)
#pragma unroll
    for (int c = 0; c < 16; ++c)
      asm("" : "+v"(Wreg[r][c]));

  // partial write base: row = lane(+64r), slot = w ^ ((lane>>3)&3)
  const int pw0 = PSTR * lane + (w ^ ((lane >> 3) & 3));
  const float bias = bhh[ocol];

  f32x2 hv[16];
#pragma unroll
  for (int j = 0; j < 8; ++j) {
    float4 v = *(const float4*)&h0_b[32 * w + 4 * j];
    hv[2 * j + 0] = f32x2{v.x, v.y};
    hv[2 * j + 1] = f32x2{v.z, v.w};
  }

  for (int c = 0; c < NCHUNK; ++c) {
    // acquire this chunk's xp halves: pure poll, no fence
    if (t == 0) poll_ge_n(wbase, nw, c + 1);
    __syncthreads();

    const int s0 = c * CHUNK;
    // sc1 reload of the two rows our pre-flag cross-chunk prefetch touched
    float xp_cur = ldg_dev(&xp_b[(size_t)s0 * Hn + ocol]);
    float xp_n1  = ldg_dev(&xp_b[(size_t)(s0 + 1) * Hn + ocol]);

    for (int ss = 0; ss < CHUNK; ++ss) {
      const int s = s0 + ss;
      // depth-2 prefetch: consumed two steps later (~1.2us of cover)
      float xp_n2 = 0.0f;
      if (s + 2 < Sn)
        xp_n2 = XP_SC1 ? ldg_dev(&xp_b[(size_t)(s + 2) * Hn + ocol])
                       : xp_b[(size_t)(s + 2) * Hn + ocol];

      // ---- FMA phase: 64 v_pk_fma_f32 per lane
      f32x2 acc0 = {0.f, 0.f}, acc1 = {0.f, 0.f};
      f32x2 acc2 = {0.f, 0.f}, acc3 = {0.f, 0.f};
#pragma unroll
      for (int cc = 0; cc < 16; ++cc) {
        asm("v_pk_fma_f32 %0, %1, %2, %0" : "+v"(acc0) : "v"(Wreg[0][cc]), "v"(hv[cc]));
        asm("v_pk_fma_f32 %0, %1, %2, %0" : "+v"(acc1) : "v"(Wreg[1][cc]), "v"(hv[cc]));
        asm("v_pk_fma_f32 %0, %1, %2, %0" : "+v"(acc2) : "v"(Wreg[2][cc]), "v"(hv[cc]));
        asm("v_pk_fma_f32 %0, %1, %2, %0" : "+v"(acc3) : "v"(Wreg[3][cc]), "v"(hv[cc]));
      }
      float* pbuf = &part[(s & 1) * PBUF];
      pbuf[pw0       ] = acc0.x + acc0.y;
      pbuf[pw0 +  640] = acc1.x + acc1.y;
      pbuf[pw0 + 1280] = acc2.x + acc2.y;
      pbuf[pw0 + 1920] = acc3.x + acc3.y;

      asm volatile("s_waitcnt lgkmcnt(0)" ::: "memory");
      __builtin_amdgcn_s_barrier();
      __builtin_amdgcn_sched_barrier(0);

      // ---- reduce: every lane sums all 8 slots of its output (no shfl)
      const f32x2* prow = (const f32x2*)&pbuf[PSTR * ocol];
      f32x2 p0 = prow[0], p1 = prow[1], p2 = prow[2], p3 = prow[3];
      f32x2 q01 = p0 + p1;          // v_pk_add_f32
      f32x2 q23 = p2 + p3;
      f32x2 qq = q01 + q23;
      float hn = tanh_fast((qq.x + qq.y) + xp_cur + bias);
      if (lane < 32) {
        hbuf[ocol] = hn;
        if (Y_SC1) stg_dev(&y_b[(size_t)s * Hn + ocol], hn);  // L3 write-through
        else       y_b[(size_t)s * Hn + ocol] = hn;           // final output
      }
      xp_cur = xp_n1;
      xp_n1 = xp_n2;

      // ---- wave-local hv reload (only this wave's own 32 outputs)
      __builtin_amdgcn_wave_barrier();   // keep reads after the masked write
#pragma unroll
      for (int j = 0; j < 8; ++j) {
        float4 v = *(const float4*)&hbuf[32 * w + 4 * j];
        hv[2 * j + 0] = f32x2{v.x, v.y};
        hv[2 * j + 1] = f32x2{v.z, v.w};
      }
    }

    if (pub) publish(pub, (unsigned)(c + 1), t);
  }

  if (lane < 32) hfin_b[ocol] = hbuf[ocol];
}

// ---------------------------------------------------------------------------
// Projection worker (unchanged r10): one block per (layer, batch, N-half).
//   C[64, 2x64] = A[64,256] * W[.,256]^T + bias, k ascending (absmax-stable)
// A,W normal cached; C (xp) sc1 write-through (consumed cross-XCD by rec).
// ~20us/chunk < rec cadence -> never gates (r8).
// ---------------------------------------------------------------------------
__device__ void proj_body(const float* __restrict__ Ab,
                          const float* __restrict__ W,
                          const float* __restrict__ bias,
                          float* __restrict__ Cb,
                          unsigned* waitf, unsigned* pub,
                          int nt0, int nt1,
                          float* smem) {
  const int t = threadIdx.x;
  const int tx = t & 15;    // 4 cols each
  const int ty = t >> 4;    // 0..31, 2 rows each
  float (*As)[68] = (float(*)[68])smem;
  float (*Bs)[68] = (float(*)[68])(smem + 64 * 68);

  for (int c = 0; c < NCHUNK; ++c) {
    if (waitf) {
      if (t == 0) poll_ge_n(waitf, 1, c + 1);
      __syncthreads();
    }
    const float* A = Ab + (size_t)(c * CHUNK) * Hn;
    float* C = Cb + (size_t)(c * CHUNK) * Hn;

    for (int nt = nt0; nt < nt1; ++nt) {
      const int n0 = nt * 64;
      float acc[2][4] = {{0.f, 0.f, 0.f, 0.f}, {0.f, 0.f, 0.f, 0.f}};
      for (int kc = 0; kc < Hn; kc += 64) {
#pragma unroll
        for (int r = 0; r < 2; ++r) {
          int idx = t + 512 * r;           // 0..1023 -> 64 rows x 16 float4
          int mm = idx >> 4;
          int kk = (idx & 15) << 2;
          float4 av = *(const float4*)&A[(size_t)mm * Hn + kc + kk];
          As[kk + 0][mm] = av.x; As[kk + 1][mm] = av.y;
          As[kk + 2][mm] = av.z; As[kk + 3][mm] = av.w;
          float4 wv = *(const float4*)&W[(size_t)(n0 + mm) * Hn + kc + kk];
          Bs[kk + 0][mm] = wv.x; Bs[kk + 1][mm] = wv.y;
          Bs[kk + 2][mm] = wv.z; Bs[kk + 3][mm] = wv.w;
        }
        __syncthreads();
#pragma unroll
        for (int k = 0; k < 64; ++k) {
          float a0 = As[k][2 * ty], a1 = As[k][2 * ty + 1];
          float4 bv = *(const float4*)&Bs[k][tx << 2];
          acc[0][0] += a0 * bv.x; acc[0][1] += a0 * bv.y;
          acc[0][2] += a0 * bv.z; acc[0][3] += a0 * bv.w;
          acc[1][0] += a1 * bv.x; acc[1][1] += a1 * bv.y;
          acc[1][2] += a1 * bv.z; acc[1][3] += a1 * bv.w;
        }
        __syncthreads();
      }
      float4 bb = *(const float4*)&bias[n0 + (tx << 2)];
#pragma unroll
      for (int i = 0; i < 2; ++i) {
        float* cp = &C[(size_t)(2 * ty + i) * Hn + n0 + (tx << 2)];
        stg_dev(cp + 0, acc[i][0] + bb.x);
        stg_dev(cp + 1, acc[i][1] + bb.y);
        stg_dev(cp + 2, acc[i][2] + bb.z);
        stg_dev(cp + 3, acc[i][3] + bb.w);
      }
    }

    publish(pub, (unsigned)(c + 1), t);
  }
}

// ---------------------------------------------------------------------------
// Fused pipeline kernel. 192 blocks x 512 threads:
//   [  0, 32): rec1, batch b      polls xp1[b] (2 flags), publishes y1[b]
//   [ 32, 64): rec2, batch b      polls xp2[b] (2 flags)
//   [ 64,128): proj1 (b, half j)  no wait; publishes xp1[b] half j
//   [128,192): proj2 (b, half j)  polls y1[b]; publishes xp2[b] half j
// In-place xp reuse is flag-ordered: proj1[c] -> rec1[c] -> (y1 flag) ->
// proj2[c] -> rec2[c]; rec1's 2-row lookahead into c+1 is disjoint and
// sc1-reloaded post-flag.
// ---------------------------------------------------------------------------
__global__ __launch_bounds__(512)
__attribute__((amdgpu_waves_per_eu(2, 2)))
void fused(
    const float* __restrict__ x, const float* __restrict__ h0,
    const float* __restrict__ Wih, const float* __restrict__ Whh,
    const float* __restrict__ bih, const float* __restrict__ bhh,
    float* __restrict__ yout, float* __restrict__ fin,
    float* __restrict__ xpws) {
  __shared__ float smem[2 * 64 * 68];   // 34.8 KB; rec carves part+hbuf
  const int bid = blockIdx.x;

  if (bid < 32) {
    const int b = bid;
    rec_body<false, true>(xpws + (size_t)b * Sn * Hn, Whh, bhh,
                          h0 + (size_t)b * Hn,
                          yout + (size_t)b * Sn * Hn, fin + (size_t)b * Hn,
                          &g_flags[(0 * Bn + b) * FPAD], 2,
                          &g_flags[(2 * Bn + b) * FPAD],
                          smem, smem + 2 * PBUF);
  } else if (bid < 64) {
    const int b = bid - 32;
    rec_body<true, false>(xpws + (size_t)b * Sn * Hn, Whh + Hn * Hn, bhh + Hn,
                          h0 + (size_t)Bn * Hn + (size_t)b * Hn,
                          yout + (size_t)b * Sn * Hn,
                          fin + (size_t)Bn * Hn + (size_t)b * Hn,
                          &g_flags[(3 * Bn + b) * FPAD], 2, nullptr,
                          smem, smem + 2 * PBUF);
  } else if (bid < 128) {
    const int q = bid - 64;
    const int b = q & 31, j = q >> 5;    // half j: tiles 2j..2j+1
    proj_body(x + (size_t)b * Sn * Hn, Wih, bih, xpws + (size_t)b * Sn * Hn,
              nullptr, &g_flags[((0 + j) * Bn + b) * FPAD],
              2 * j, 2 * j + 2, smem);
  } else {
    const int q = bid - 128;
    const int b = q & 31, j = q >> 5;    // half j: tiles 2j..2j+1
    proj_body(yout + (size_t)b * Sn * Hn, Wih + Hn * Hn, bih + Hn,
              xpws + (size_t)b * Sn * Hn,
              &g_flags[(2 * Bn + b) * FPAD],
              &g_flags[((3 + j) * Bn + b) * FPAD],
              2 * j, 2 * j + 2, smem);
  }
}

// ---------------------------------------------------------------------------
// Launch: zero flags, then the single fully-pipelined kernel.
// ws needs Bn*Sn*Hn*4 = 64 MiB (xp buffer, shared by both layers in-place).
// ---------------------------------------------------------------------------
extern "C" void kernel_launch(void* const* d_in, const int* in_sizes, int n_in,
                              void* d_out, int out_size, void* d_ws, size_t ws_size,
                              hipStream_t stream) {
  const float* x   = (const float*)d_in[0];
  const float* h0  = (const float*)d_in[1];
  const float* Wih = (const float*)d_in[2];
  const float* Whh = (const float*)d_in[3];
  const float* bih = (const float*)d_in[4];
  const float* bhh = (const float*)d_in[5];

  float* out = (float*)d_out;
  float* yout = out;                              // [Bn,Sn,Hn]
  float* fin  = out + (size_t)Bn * Sn * Hn;       // [Ln,Bn,Hn]
  float* xpws = (float*)d_ws;                     // [Bn,Sn,Hn] scratch

  zero_flags_k<<<1, 256, 0, stream>>>();
  fused<<<192, 512, 0, stream>>>(x, h0, Wih, Whh, bih, bhh, yout, fin, xpws);
}